// Round 6
// baseline (273.305 us; speedup 1.0000x reference)
//
#include <hip/hip_runtime.h>
#include <math.h>

#define NGRAPH 128
#define KTOP 30
#define LATENT 193
#define HID 64

typedef unsigned short u16;

// ---------------- zero edeg (own kernel; rocclr fill showed 45us) ------------
__global__ void k_zero(int* edeg, int n) {
    int i = blockIdx.x * blockDim.x + threadIdx.x;
    if (i < n) edeg[i] = 0;
}

// ---- K1: fused layer-1 GEMM (raw) + edge hist/rank (1 edge/thread) + starts ----
// bid%5==0 -> gemm block (782); else hist block (3125, 1 atomic per thread)
__global__ __launch_bounds__(256) void k_gemm_hist(
        const float* __restrict__ A, const float* __restrict__ W,
        float* __restrict__ Hs, int M, int K, int NG,
        const int* __restrict__ dst, const int* __restrict__ batch,
        int* edeg, u16* __restrict__ rank, int* starts,
        int E, int n) {
    __shared__ float As[64][17];
    __shared__ float Bs[16][65];
    int bid = blockIdx.x;
    int gemm_id = (bid % 5 == 0) ? bid / 5 : -1;
    if (gemm_id >= 0 && gemm_id < NG) {
        int tid = threadIdx.x;
        int tx = tid & 15, ty = tid >> 4;
        int br = gemm_id * 64;
        float c[4][4] = {};
        for (int k0 = 0; k0 < K; k0 += 16) {
            {
                int idx = tid * 4;
                int r = idx >> 4;
                int kk = idx & 15;
                int grow = br + r;
                float4 v = make_float4(0.f, 0.f, 0.f, 0.f);
                if (grow < M) v = *(const float4*)(A + (size_t)grow * K + k0 + kk);
                As[r][kk + 0] = v.x; As[r][kk + 1] = v.y;
                As[r][kk + 2] = v.z; As[r][kk + 3] = v.w;
            }
            {
                int idx = tid * 4;
                int kk = idx >> 6;
                int col = idx & 63;
                float4 v = *(const float4*)(W + (size_t)(k0 + kk) * 64 + col);
                Bs[kk][col + 0] = v.x; Bs[kk][col + 1] = v.y;
                Bs[kk][col + 2] = v.z; Bs[kk][col + 3] = v.w;
            }
            __syncthreads();
#pragma unroll
            for (int kk = 0; kk < 16; ++kk) {
                float a[4], b[4];
#pragma unroll
                for (int i = 0; i < 4; i++) a[i] = As[ty + i * 16][kk];
#pragma unroll
                for (int j = 0; j < 4; j++) b[j] = Bs[kk][tx + j * 16];
#pragma unroll
                for (int i = 0; i < 4; i++)
#pragma unroll
                    for (int j = 0; j < 4; j++) c[i][j] += a[i] * b[j];
            }
            __syncthreads();
        }
#pragma unroll
        for (int i = 0; i < 4; i++) {
            int row = br + ty + i * 16;
            if (row >= M) continue;
#pragma unroll
            for (int j = 0; j < 4; j++) {
                int col = tx + j * 16;
                Hs[(size_t)row * HID + col] = c[i][j];   // raw (dinv deferred)
            }
        }
    } else {
        int ngb = min((bid + 4) / 5, NG);
        int fid = bid - ngb;                 // 0..NH-1
        int gi = fid * 256 + threadIdx.x;    // one edge per thread
        if (gi < n) {
            int b = batch[gi];
            if (gi == 0) {
                for (int g = 0; g <= b; g++) starts[g] = 0;
            } else {
                int pb = batch[gi - 1];
                for (int g = pb + 1; g <= b; g++) starts[g] = gi;
            }
            if (gi == n - 1) {
                for (int g = b + 1; g <= NGRAPH; g++) starts[g] = n;
            }
        }
        if (gi < E) {
            int d = dst[gi];
            rank[gi] = (u16)atomicAdd(&edeg[d], 1);
        }
    }
}

// ---------------- scan stage 1: local exclusive scan + block sums (+ dinv) ---
__global__ void k_scan1(const int* __restrict__ edeg, int* offs, int* bsum,
                        float* dinv, int n) {
    __shared__ int s[256];
    int t = threadIdx.x;
    int gi = blockIdx.x * 256 + t;
    int v = (gi < n) ? edeg[gi] : 0;
    if (gi < n) dinv[gi] = rsqrtf((float)(v + 1));   // +1 self-loop
    s[t] = v;
    __syncthreads();
    for (int o = 1; o < 256; o <<= 1) {
        int add = (t >= o) ? s[t - o] : 0;
        __syncthreads();
        s[t] += add;
        __syncthreads();
    }
    if (gi < n) offs[gi] = s[t] - v;          // local exclusive
    if (t == 255) bsum[blockIdx.x] = s[255];
}

// ---------------- scan stage 2+3 fused: every block scans bsum in LDS --------
__global__ void k_scan23(int* offs, const int* __restrict__ bsum,
                         int n, int E, int nb) {
    __shared__ int s[256];
    int t = threadIdx.x;
    int bid = blockIdx.x;
    int v = (t < nb) ? bsum[t] : 0;
    s[t] = v;
    __syncthreads();
    for (int o = 1; o < 256; o <<= 1) {
        int add = (t >= o) ? s[t - o] : 0;
        __syncthreads();
        s[t] += add;
        __syncthreads();
    }
    int boffv = (bid == 0) ? 0 : s[bid - 1];
    int gi = bid * 256 + t;
    if (gi < n) offs[gi] += boffv;
    if (gi == 0) offs[n] = E;
}

// ---------------- CSR fill, NO atomics: csr[offs[dst]+rank] = src ------------
__global__ __launch_bounds__(256) void k_fill(const int* __restrict__ src,
                                              const int* __restrict__ dst,
                                              const u16* __restrict__ rank,
                                              const int* __restrict__ offs,
                                              u16* __restrict__ csr, int E) {
    int t = blockIdx.x * 256 + threadIdx.x;
    int e0 = t * 4;
    if (e0 + 4 <= E) {
        int4 s4 = *(const int4*)(src + e0);
        int4 d4 = *(const int4*)(dst + e0);
        const u16* rp = rank + e0;
        csr[offs[d4.x] + rp[0]] = (u16)s4.x;
        csr[offs[d4.y] + rp[1]] = (u16)s4.y;
        csr[offs[d4.z] + rp[2]] = (u16)s4.z;
        csr[offs[d4.w] + rp[3]] = (u16)s4.w;
    } else {
        for (int e = e0; e < E; e++)
            csr[offs[dst[e]] + rank[e]] = (u16)src[e];
    }
}

// ---------------- plain GEMM (layers 2,3): Hs = (A @ W) * dinv[row] ----------
__global__ __launch_bounds__(256) void k_gemm(const float* __restrict__ A,
                                              const float* __restrict__ W,
                                              const float* __restrict__ dinv,
                                              float* __restrict__ Hs,
                                              int M, int K) {
    __shared__ float As[64][17];
    __shared__ float Bs[16][65];
    int tid = threadIdx.x;
    int tx = tid & 15, ty = tid >> 4;
    int br = blockIdx.x * 64;
    float c[4][4] = {};
    for (int k0 = 0; k0 < K; k0 += 16) {
        {
            int idx = tid * 4;
            int r = idx >> 4;
            int kk = idx & 15;
            int grow = br + r;
            float4 v = make_float4(0.f, 0.f, 0.f, 0.f);
            if (grow < M) v = *(const float4*)(A + (size_t)grow * K + k0 + kk);
            As[r][kk + 0] = v.x; As[r][kk + 1] = v.y;
            As[r][kk + 2] = v.z; As[r][kk + 3] = v.w;
        }
        {
            int idx = tid * 4;
            int kk = idx >> 6;
            int col = idx & 63;
            float4 v = *(const float4*)(W + (size_t)(k0 + kk) * 64 + col);
            Bs[kk][col + 0] = v.x; Bs[kk][col + 1] = v.y;
            Bs[kk][col + 2] = v.z; Bs[kk][col + 3] = v.w;
        }
        __syncthreads();
#pragma unroll
        for (int kk = 0; kk < 16; ++kk) {
            float a[4], b[4];
#pragma unroll
            for (int i = 0; i < 4; i++) a[i] = As[ty + i * 16][kk];
#pragma unroll
            for (int j = 0; j < 4; j++) b[j] = Bs[kk][tx + j * 16];
#pragma unroll
            for (int i = 0; i < 4; i++)
#pragma unroll
                for (int j = 0; j < 4; j++) c[i][j] += a[i] * b[j];
        }
        __syncthreads();
    }
#pragma unroll
    for (int i = 0; i < 4; i++) {
        int row = br + ty + i * 16;
        if (row >= M) continue;
        float d = dinv[row];
#pragma unroll
        for (int j = 0; j < 4; j++) {
            int col = tx + j * 16;
            Hs[(size_t)row * HID + col] = c[i][j] * d;
        }
    }
}

// ------- aggregate (gather, wave per node) + fused tanh epilogue -------
template <bool DEFER, bool FUSE_TS>
__global__ __launch_bounds__(256) void k_agg(const float* __restrict__ Hs,
                                             const u16* __restrict__ csr,
                                             const int* __restrict__ offs,
                                             const float* __restrict__ dinv,
                                             const float* __restrict__ b,
                                             float* __restrict__ H, int n,
                                             const float* __restrict__ w3,
                                             float* __restrict__ ts) {
    int wid = threadIdx.x >> 6;
    int lane = threadIdx.x & 63;
    int node = blockIdx.x * 4 + wid;
    if (node >= n) return;
    float d = dinv[node];
    float acc = Hs[(size_t)node * HID + lane];
    if (DEFER) acc *= d;
    int s = offs[node], e = offs[node + 1];
    int i = s;
    for (; i + 8 <= e; i += 8) {
        float part = 0.f;
#pragma unroll
        for (int k = 0; k < 8; k++) {
            int u = csr[i + k];
            float v = Hs[(size_t)u * HID + lane];
            if (DEFER) v *= dinv[u];
            part += v;
        }
        acc += part;
    }
    for (; i < e; i++) {
        int u = csr[i];
        float v = Hs[(size_t)u * HID + lane];
        if (DEFER) v *= dinv[u];
        acc += v;
    }
    float h = tanhf(acc * d + b[lane]);
    H[(size_t)node * HID + lane] = h;
    if (FUSE_TS) {
        float v = h * w3[lane];
        for (int o = 32; o > 0; o >>= 1) v += __shfl_down(v, o, 64);
        if (lane == 0) ts[node] = v * d;
    }
}

// layer-4 aggregate + finish
__global__ void k_agg4(const float* __restrict__ ts, const u16* __restrict__ csr,
                       const int* __restrict__ offs, const float* __restrict__ dinv,
                       const float* __restrict__ b3, float* h4, int n) {
    int node = blockIdx.x * blockDim.x + threadIdx.x;
    if (node >= n) return;
    float acc = ts[node];
    int s = offs[node], e = offs[node + 1];
    for (int i = s; i < e; i++) acc += ts[csr[i]];
    h4[node] = tanhf(acc * dinv[node] + b3[0]);
}

// ---------------- fused: single-pass rank top-K select + tail ----------------
__global__ __launch_bounds__(1024) void k_select_tail(
        const float* __restrict__ h1, const float* __restrict__ h2,
        const float* __restrict__ h3, const float* __restrict__ h4,
        const int* __restrict__ starts,
        const float* __restrict__ c1w, const float* __restrict__ c1b,
        const float* __restrict__ c2w, const float* __restrict__ c2b,
        const float* __restrict__ l1w, const float* __restrict__ l1b,
        const float* __restrict__ l2w, const float* __restrict__ l2b,
        float* __restrict__ out) {
    __shared__ float p[KTOP * LATENT];    // 5790
    __shared__ float w1s[16 * LATENT];    // 3088
    __shared__ float w2s[32 * 16 * 5];    // 2560
    __shared__ float vv[1024];
    __shared__ int   sel_s[KTOP];
    __shared__ float z1[16 * KTOP];
    __shared__ float z1p[16 * 15];
    __shared__ float flat[352];
    __shared__ float part[1024];
    __shared__ float y1[256];
    int g = blockIdx.x;
    int t = threadIdx.x;
    int s = starts[g], c = starts[g + 1] - s;

    // weight loads overlap with select
    for (int i = t; i < 16 * LATENT; i += 1024) w1s[i] = c1w[i];
    for (int i = t; i < 32 * 16 * 5; i += 1024) w2s[i] = c2w[i];
    if (t < KTOP) sel_s[t] = -1;

    // ---- select: rank_i = #{j: v_j > v_i or (v_j==v_i && j<i)} ----
    if (c <= 1024) {
        for (int i = t; i < c; i += 1024) vv[i] = h4[s + i];
        __syncthreads();
        for (int i = t; i < c; i += 1024) {
            float vi = vv[i];
            int r = 0;
            for (int j = 0; j < c; j++) {
                float vj = vv[j];
                r += (vj > vi) || (vj == vi && j < i);
            }
            if (r < KTOP) sel_s[r] = s + i;
        }
    } else {
        __syncthreads();
        for (int i = t; i < c; i += 1024) {
            float vi = h4[s + i];
            int r = 0;
            for (int j = 0; j < c; j++) {
                float vj = h4[s + j];
                r += (vj > vi) || (vj == vi && j < i);
            }
            if (r < KTOP) sel_s[r] = s + i;
        }
    }
    __syncthreads();

    // ---- gather latent rows ----
    for (int i = t; i < KTOP * LATENT; i += 1024) {
        int slot = i / LATENT;
        int j = i - slot * LATENT;
        int node = sel_s[slot];
        float v = 0.f;
        if (node >= 0) {
            if (j < 64)       v = h1[(size_t)node * HID + j];
            else if (j < 128) v = h2[(size_t)node * HID + j - 64];
            else if (j < 192) v = h3[(size_t)node * HID + j - 128];
            else              v = h4[node];
        }
        p[i] = v;
    }
    __syncthreads();
    // conv1 193->16 + relu
    if (t < 16 * KTOP) {
        int ch = t / KTOP, tt = t - ch * KTOP;
        float sa = c1b[ch];
        const float* wp = &w1s[ch * LATENT];
        const float* pp = &p[tt * LATENT];
        for (int j = 0; j < LATENT; j++) sa += pp[j] * wp[j];
        z1[ch * KTOP + tt] = fmaxf(sa, 0.f);
    }
    __syncthreads();
    if (t < 16 * 15) {
        int ch = t / 15, tt = t - ch * 15;
        z1p[t] = fmaxf(z1[ch * KTOP + 2 * tt], z1[ch * KTOP + 2 * tt + 1]);
    }
    __syncthreads();
    if (t < 32 * 11) {
        int c2 = t / 11, tt = t - c2 * 11;
        float sa = c2b[c2];
        for (int c1i = 0; c1i < 16; c1i++) {
            const float* wp = &w2s[(c2 * 16 + c1i) * 5];
            const float* zp = &z1p[c1i * 15 + tt];
#pragma unroll
            for (int dt = 0; dt < 5; dt++) sa += zp[dt] * wp[dt];
        }
        flat[c2 * 11 + tt] = fmaxf(sa, 0.f);
    }
    __syncthreads();
    {
        int o = t & 255, ch = t >> 8;
        int i0 = ch * 88, i1 = i0 + 88;
        float sa = 0.f;
        for (int i = i0; i < i1; i++) sa += flat[i] * l1w[(size_t)i * 256 + o];
        part[t] = sa;
    }
    __syncthreads();
    if (t < 256)
        y1[t] = fmaxf(part[t] + part[256 + t] + part[512 + t] + part[768 + t] + l1b[t], 0.f);
    __syncthreads();
    if (t < 128) {
        int o = t >> 6, lane = t & 63;
        float sa = 0.f;
        for (int i = lane; i < 256; i += 64) sa += y1[i] * l2w[(size_t)i * 2 + o];
        for (int off = 32; off > 0; off >>= 1) sa += __shfl_down(sa, off, 64);
        if (lane == 0) out[g * 2 + o] = sa + l2b[o];
    }
}

// ---------------- launch ----------------
static inline char* align256(char* p) {
    return (char*)(((uintptr_t)p + 255) & ~(uintptr_t)255);
}

extern "C" void kernel_launch(void* const* d_in, const int* in_sizes, int n_in,
                              void* d_out, int out_size, void* d_ws, size_t ws_size,
                              hipStream_t stream) {
    const float* x     = (const float*)d_in[0];
    const int*  eidx   = (const int*)d_in[1];
    const int*  batch  = (const int*)d_in[2];
    const float* w0    = (const float*)d_in[3];
    const float* b0    = (const float*)d_in[4];
    const float* w1    = (const float*)d_in[5];
    const float* b1    = (const float*)d_in[6];
    const float* w2    = (const float*)d_in[7];
    const float* b2    = (const float*)d_in[8];
    const float* w3    = (const float*)d_in[9];
    const float* b3    = (const float*)d_in[10];
    const float* c1w   = (const float*)d_in[11];
    const float* c1b   = (const float*)d_in[12];
    const float* c2w   = (const float*)d_in[13];
    const float* c2b   = (const float*)d_in[14];
    const float* l1w   = (const float*)d_in[15];
    const float* l1b   = (const float*)d_in[16];
    const float* l2w   = (const float*)d_in[17];
    const float* l2b   = (const float*)d_in[18];

    int N = in_sizes[2];              // 50000 nodes
    int E = in_sizes[1] / 2;          // 800000 edges
    int K0 = in_sizes[0] / N;         // 128 input feats
    const int* esrc = eidx;
    const int* edst = eidx + E;

    char* w = (char*)d_ws;
    float* dinv  = (float*)w;             w = align256(w + (size_t)N * 4);
    int*   edeg  = (int*)w;               w = align256(w + (size_t)N * 4);
    int*   offs  = (int*)w;               w = align256(w + (size_t)(N + 1) * 4);
    int*   bsum  = (int*)w;               w = align256(w + 1024);
    float* ts    = (float*)w;             w = align256(w + (size_t)N * 4);
    float* h4    = (float*)w;             w = align256(w + (size_t)N * 4);
    int* starts  = (int*)w;               w = align256(w + (NGRAPH + 1) * 4);
    u16* rank    = (u16*)w;               w = align256(w + (size_t)E * 2);
    u16* csr     = (u16*)w;               w = align256(w + (size_t)E * 2);
    float* Hs    = (float*)w;             w = align256(w + (size_t)N * HID * 4);
    float* h1    = (float*)w;             w = align256(w + (size_t)N * HID * 4);
    float* h2    = (float*)w;             w = align256(w + (size_t)N * HID * 4);
    float* h3    = (float*)w;             w = align256(w + (size_t)N * HID * 4);

    int nb = (N + 255) / 256;             // 196
    int NG = (N + 63) / 64;               // 782
    int NH = (E + 255) / 256;             // 3125 (1 edge per thread)
    int agg_grid = (N + 3) / 4;

    // zero degree array (own kernel; rocclr memset showed 45us)
    k_zero<<<nb, 256, 0, stream>>>(edeg, N);

    // K1: layer-1 GEMM (raw) || edge histogram+rank || graph starts
    k_gemm_hist<<<NG + NH, 256, 0, stream>>>(x, w0, Hs, N, K0, NG,
                                             edst, batch, edeg, rank, starts, E, N);

    // CSR offsets (hierarchical scan, stage2+3 fused) + dinv
    k_scan1<<<nb, 256, 0, stream>>>(edeg, offs, bsum, dinv, N);
    k_scan23<<<nb, 256, 0, stream>>>(offs, bsum, N, E, nb);

    // CSR fill (no atomics)
    k_fill<<<(E / 4 + 255) / 256 + 1, 256, 0, stream>>>(esrc, edst, rank, offs, csr, E);

    // layer 1 aggregate (deferred dinv on gathered rows)
    k_agg<true, false><<<agg_grid, 256, 0, stream>>>(Hs, csr, offs, dinv, b0, h1, N, nullptr, nullptr);
    // layer 2
    k_gemm<<<NG, 256, 0, stream>>>(h1, w1, dinv, Hs, N, HID);
    k_agg<false, false><<<agg_grid, 256, 0, stream>>>(Hs, csr, offs, dinv, b1, h2, N, nullptr, nullptr);
    // layer 3 (+ fused layer-4 prescaled GEMV -> ts)
    k_gemm<<<NG, 256, 0, stream>>>(h2, w2, dinv, Hs, N, HID);
    k_agg<false, true><<<agg_grid, 256, 0, stream>>>(Hs, csr, offs, dinv, b2, h3, N, w3, ts);
    // layer 4 aggregate + finish
    k_agg4<<<nb, 256, 0, stream>>>(ts, csr, offs, dinv, b3, h4, N);

    // fused top-30 select + tail
    k_select_tail<<<NGRAPH, 1024, 0, stream>>>(h1, h2, h3, h4, starts,
                                               c1w, c1b, c2w, c2b,
                                               l1w, l1b, l2w, l2b,
                                               (float*)d_out);
}

// Round 7
// 252.522 us; speedup vs baseline: 1.0823x; 1.0823x over previous
//
#include <hip/hip_runtime.h>
#include <math.h>

#define NGRAPH 128
#define KTOP 30
#define LATENT 193
#define HID 64

typedef unsigned short u16;

// ---------------- zero edeg (own kernel; rocclr fill showed 45us) ------------
__global__ void k_zero(int* edeg, int n) {
    int i = blockIdx.x * blockDim.x + threadIdx.x;
    if (i < n) edeg[i] = 0;
}

// ---------------- shared GEMM tile: 64x64 out, BK=32, k-major LDS ------------
// As[kk][row], Bs[kk][col] (stride 68). Per-thread 4x4: rows ty*4..+3, cols tx*4..+3.
// Inner loop: 2x ds_read_b128 per kk (vs 8x b32 before) -> VALU-bound.
template <bool SCALE>
__device__ __forceinline__ void gemm_tile(const float* __restrict__ A,
                                          const float* __restrict__ W,
                                          const float* __restrict__ dinv,
                                          float* __restrict__ Hs,
                                          int M, int K, int br,
                                          float (*As)[68], float (*Bs)[68]) {
    int tid = threadIdx.x;
    int tx = tid & 15, ty = tid >> 4;
    int kA = (tid & 7) * 4;   // k-offset for A staging
    int rA = tid >> 3;        // row 0..31
    int kB = tid >> 3;        // k-row for B staging
    int cB = (tid & 7) * 8;   // col 0..56
    float c[4][4] = {};
    for (int k0 = 0; k0 < K; k0 += 32) {
        // stage A (transposed to k-major): 2 x (32 rows x 32 k)
#pragma unroll
        for (int it = 0; it < 2; ++it) {
            int row = it * 32 + rA;
            int grow = br + row;
            float4 v = make_float4(0.f, 0.f, 0.f, 0.f);
            if (grow < M) v = *(const float4*)(A + (size_t)grow * K + k0 + kA);
            As[kA + 0][row] = v.x;
            As[kA + 1][row] = v.y;
            As[kA + 2][row] = v.z;
            As[kA + 3][row] = v.w;
        }
        // stage B (already k-major): 32 k x 64 col
        {
            const float* wp = W + (size_t)(k0 + kB) * 64 + cB;
            float4 v0 = *(const float4*)(wp);
            float4 v1 = *(const float4*)(wp + 4);
            *(float4*)&Bs[kB][cB] = v0;
            *(float4*)&Bs[kB][cB + 4] = v1;
        }
        __syncthreads();
#pragma unroll
        for (int kk = 0; kk < 32; ++kk) {
            float4 a4 = *(const float4*)&As[kk][ty * 4];
            float4 b4 = *(const float4*)&Bs[kk][tx * 4];
            c[0][0] += a4.x * b4.x; c[0][1] += a4.x * b4.y; c[0][2] += a4.x * b4.z; c[0][3] += a4.x * b4.w;
            c[1][0] += a4.y * b4.x; c[1][1] += a4.y * b4.y; c[1][2] += a4.y * b4.z; c[1][3] += a4.y * b4.w;
            c[2][0] += a4.z * b4.x; c[2][1] += a4.z * b4.y; c[2][2] += a4.z * b4.z; c[2][3] += a4.z * b4.w;
            c[3][0] += a4.w * b4.x; c[3][1] += a4.w * b4.y; c[3][2] += a4.w * b4.z; c[3][3] += a4.w * b4.w;
        }
        __syncthreads();
    }
#pragma unroll
    for (int i = 0; i < 4; i++) {
        int row = br + ty * 4 + i;
        if (row >= M) continue;
        float d = SCALE ? dinv[row] : 1.f;
        float4 o;
        o.x = c[i][0] * d; o.y = c[i][1] * d; o.z = c[i][2] * d; o.w = c[i][3] * d;
        *(float4*)(Hs + (size_t)row * HID + tx * 4) = o;
    }
}

// ---- K1: fused layer-1 GEMM (raw) + edge hist/rank (4 edges/thr) + starts ----
// even blocks: gemm; odd blocks: hist (REVERTED to round-5 proven structure)
__global__ __launch_bounds__(256) void k_gemm_hist(
        const float* __restrict__ A, const float* __restrict__ W,
        float* __restrict__ Hs, int M, int K, int NG,
        const int* __restrict__ dst, const int* __restrict__ batch,
        int* edeg, u16* __restrict__ rank, int* starts,
        int E, int n, int NH) {
    __shared__ float As[32][68];
    __shared__ float Bs[32][68];
    int bid = blockIdx.x;
    if ((bid & 1) == 0) {
        int gid = bid >> 1;
        if (gid >= NG) return;
        gemm_tile<false>(A, W, nullptr, Hs, M, K, gid * 64, As, Bs);
    } else {
        int fid = bid >> 1;
        if (fid >= NH) return;
        int t = threadIdx.x;
        int gi = fid * 256 + t;
        if (gi < n) {
            int b = batch[gi];
            if (gi == 0) {
                for (int g = 0; g <= b; g++) starts[g] = 0;
            } else {
                int pb = batch[gi - 1];
                for (int g = pb + 1; g <= b; g++) starts[g] = gi;
            }
            if (gi == n - 1) {
                for (int g = b + 1; g <= NGRAPH; g++) starts[g] = n;
            }
        }
        int base = fid * 1024;
#pragma unroll
        for (int k = 0; k < 4; k++) {
            int e = base + k * 256 + t;
            if (e < E) {
                int d = dst[e];
                rank[e] = (u16)atomicAdd(&edeg[d], 1);
            }
        }
    }
}

// ---------------- scan stage 1: local exclusive scan + block sums (+ dinv) ---
__global__ void k_scan1(const int* __restrict__ edeg, int* offs, int* bsum,
                        float* dinv, int n) {
    __shared__ int s[256];
    int t = threadIdx.x;
    int gi = blockIdx.x * 256 + t;
    int v = (gi < n) ? edeg[gi] : 0;
    if (gi < n) dinv[gi] = rsqrtf((float)(v + 1));   // +1 self-loop
    s[t] = v;
    __syncthreads();
    for (int o = 1; o < 256; o <<= 1) {
        int add = (t >= o) ? s[t - o] : 0;
        __syncthreads();
        s[t] += add;
        __syncthreads();
    }
    if (gi < n) offs[gi] = s[t] - v;          // local exclusive
    if (t == 255) bsum[blockIdx.x] = s[255];
}

// ---------------- scan stage 2+3 fused: every block scans bsum in LDS --------
__global__ void k_scan23(int* offs, const int* __restrict__ bsum,
                         int n, int E, int nb) {
    __shared__ int s[256];
    int t = threadIdx.x;
    int bid = blockIdx.x;
    int v = (t < nb) ? bsum[t] : 0;
    s[t] = v;
    __syncthreads();
    for (int o = 1; o < 256; o <<= 1) {
        int add = (t >= o) ? s[t - o] : 0;
        __syncthreads();
        s[t] += add;
        __syncthreads();
    }
    int boffv = (bid == 0) ? 0 : s[bid - 1];
    int gi = bid * 256 + t;
    if (gi < n) offs[gi] += boffv;
    if (gi == 0) offs[n] = E;
}

// ---------------- CSR fill, NO atomics: csr[offs[dst]+rank] = src ------------
__global__ __launch_bounds__(256) void k_fill(const int* __restrict__ src,
                                              const int* __restrict__ dst,
                                              const u16* __restrict__ rank,
                                              const int* __restrict__ offs,
                                              u16* __restrict__ csr, int E) {
    int t = blockIdx.x * 256 + threadIdx.x;
    int e0 = t * 4;
    if (e0 + 4 <= E) {
        int4 s4 = *(const int4*)(src + e0);
        int4 d4 = *(const int4*)(dst + e0);
        uint2 rv = *(const uint2*)(rank + e0);
        csr[offs[d4.x] + (rv.x & 0xffff)] = (u16)s4.x;
        csr[offs[d4.y] + (rv.x >> 16)]    = (u16)s4.y;
        csr[offs[d4.z] + (rv.y & 0xffff)] = (u16)s4.z;
        csr[offs[d4.w] + (rv.y >> 16)]    = (u16)s4.w;
    } else {
        for (int e = e0; e < E; e++)
            csr[offs[dst[e]] + rank[e]] = (u16)src[e];
    }
}

// ---------------- plain GEMM (layers 2,3): Hs = (A @ W) * dinv[row] ----------
__global__ __launch_bounds__(256) void k_gemm(const float* __restrict__ A,
                                              const float* __restrict__ W,
                                              const float* __restrict__ dinv,
                                              float* __restrict__ Hs,
                                              int M, int K) {
    __shared__ float As[32][68];
    __shared__ float Bs[32][68];
    gemm_tile<true>(A, W, dinv, Hs, M, K, blockIdx.x * 64, As, Bs);
}

// ------- aggregate (gather, wave per node) + fused tanh epilogue -------
template <bool DEFER, bool FUSE_TS>
__global__ __launch_bounds__(256) void k_agg(const float* __restrict__ Hs,
                                             const u16* __restrict__ csr,
                                             const int* __restrict__ offs,
                                             const float* __restrict__ dinv,
                                             const float* __restrict__ b,
                                             float* __restrict__ H, int n,
                                             const float* __restrict__ w3,
                                             float* __restrict__ ts) {
    int wid = threadIdx.x >> 6;
    int lane = threadIdx.x & 63;
    int node = blockIdx.x * 4 + wid;
    if (node >= n) return;
    float d = dinv[node];
    float acc = Hs[(size_t)node * HID + lane];
    if (DEFER) acc *= d;
    int s = offs[node], e = offs[node + 1];
    int i = s;
    for (; i + 8 <= e; i += 8) {
        float part = 0.f;
#pragma unroll
        for (int k = 0; k < 8; k++) {
            int u = csr[i + k];
            float v = Hs[(size_t)u * HID + lane];
            if (DEFER) v *= dinv[u];
            part += v;
        }
        acc += part;
    }
    for (; i < e; i++) {
        int u = csr[i];
        float v = Hs[(size_t)u * HID + lane];
        if (DEFER) v *= dinv[u];
        acc += v;
    }
    float h = tanhf(acc * d + b[lane]);
    H[(size_t)node * HID + lane] = h;
    if (FUSE_TS) {
        float v = h * w3[lane];
        for (int o = 32; o > 0; o >>= 1) v += __shfl_down(v, o, 64);
        if (lane == 0) ts[node] = v * d;
    }
}

// layer-4 aggregate + finish
__global__ void k_agg4(const float* __restrict__ ts, const u16* __restrict__ csr,
                       const int* __restrict__ offs, const float* __restrict__ dinv,
                       const float* __restrict__ b3, float* h4, int n) {
    int node = blockIdx.x * blockDim.x + threadIdx.x;
    if (node >= n) return;
    float acc = ts[node];
    int s = offs[node], e = offs[node + 1];
    for (int i = s; i < e; i++) acc += ts[csr[i]];
    h4[node] = tanhf(acc * dinv[node] + b3[0]);
}

// ---------------- fused: single-pass rank top-K select + tail ----------------
__global__ __launch_bounds__(1024) void k_select_tail(
        const float* __restrict__ h1, const float* __restrict__ h2,
        const float* __restrict__ h3, const float* __restrict__ h4,
        const int* __restrict__ starts,
        const float* __restrict__ c1w, const float* __restrict__ c1b,
        const float* __restrict__ c2w, const float* __restrict__ c2b,
        const float* __restrict__ l1w, const float* __restrict__ l1b,
        const float* __restrict__ l2w, const float* __restrict__ l2b,
        float* __restrict__ out) {
    __shared__ float p[KTOP * LATENT];
    __shared__ float w1s[16 * LATENT];
    __shared__ float w2s[32 * 16 * 5];
    __shared__ float vv[1024];
    __shared__ int   sel_s[KTOP];
    __shared__ float z1[16 * KTOP];
    __shared__ float z1p[16 * 15];
    __shared__ float flat[352];
    __shared__ float part[1024];
    __shared__ float y1[256];
    int g = blockIdx.x;
    int t = threadIdx.x;
    int s = starts[g], c = starts[g + 1] - s;

    for (int i = t; i < 16 * LATENT; i += 1024) w1s[i] = c1w[i];
    for (int i = t; i < 32 * 16 * 5; i += 1024) w2s[i] = c2w[i];
    if (t < KTOP) sel_s[t] = -1;

    if (c <= 1024) {
        for (int i = t; i < c; i += 1024) vv[i] = h4[s + i];
        __syncthreads();
        for (int i = t; i < c; i += 1024) {
            float vi = vv[i];
            int r = 0;
            for (int j = 0; j < c; j++) {
                float vj = vv[j];
                r += (vj > vi) || (vj == vi && j < i);
            }
            if (r < KTOP) sel_s[r] = s + i;
        }
    } else {
        __syncthreads();
        for (int i = t; i < c; i += 1024) {
            float vi = h4[s + i];
            int r = 0;
            for (int j = 0; j < c; j++) {
                float vj = h4[s + j];
                r += (vj > vi) || (vj == vi && j < i);
            }
            if (r < KTOP) sel_s[r] = s + i;
        }
    }
    __syncthreads();

    for (int i = t; i < KTOP * LATENT; i += 1024) {
        int slot = i / LATENT;
        int j = i - slot * LATENT;
        int node = sel_s[slot];
        float v = 0.f;
        if (node >= 0) {
            if (j < 64)       v = h1[(size_t)node * HID + j];
            else if (j < 128) v = h2[(size_t)node * HID + j - 64];
            else if (j < 192) v = h3[(size_t)node * HID + j - 128];
            else              v = h4[node];
        }
        p[i] = v;
    }
    __syncthreads();
    if (t < 16 * KTOP) {
        int ch = t / KTOP, tt = t - ch * KTOP;
        float sa = c1b[ch];
        const float* wp = &w1s[ch * LATENT];
        const float* pp = &p[tt * LATENT];
        for (int j = 0; j < LATENT; j++) sa += pp[j] * wp[j];
        z1[ch * KTOP + tt] = fmaxf(sa, 0.f);
    }
    __syncthreads();
    if (t < 16 * 15) {
        int ch = t / 15, tt = t - ch * 15;
        z1p[t] = fmaxf(z1[ch * KTOP + 2 * tt], z1[ch * KTOP + 2 * tt + 1]);
    }
    __syncthreads();
    if (t < 32 * 11) {
        int c2 = t / 11, tt = t - c2 * 11;
        float sa = c2b[c2];
        for (int c1i = 0; c1i < 16; c1i++) {
            const float* wp = &w2s[(c2 * 16 + c1i) * 5];
            const float* zp = &z1p[c1i * 15 + tt];
#pragma unroll
            for (int dt = 0; dt < 5; dt++) sa += zp[dt] * wp[dt];
        }
        flat[c2 * 11 + tt] = fmaxf(sa, 0.f);
    }
    __syncthreads();
    {
        int o = t & 255, ch = t >> 8;
        int i0 = ch * 88, i1 = i0 + 88;
        float sa = 0.f;
        for (int i = i0; i < i1; i++) sa += flat[i] * l1w[(size_t)i * 256 + o];
        part[t] = sa;
    }
    __syncthreads();
    if (t < 256)
        y1[t] = fmaxf(part[t] + part[256 + t] + part[512 + t] + part[768 + t] + l1b[t], 0.f);
    __syncthreads();
    if (t < 128) {
        int o = t >> 6, lane = t & 63;
        float sa = 0.f;
        for (int i = lane; i < 256; i += 64) sa += y1[i] * l2w[(size_t)i * 2 + o];
        for (int off = 32; off > 0; off >>= 1) sa += __shfl_down(sa, off, 64);
        if (lane == 0) out[g * 2 + o] = sa + l2b[o];
    }
}

// ---------------- launch ----------------
static inline char* align256(char* p) {
    return (char*)(((uintptr_t)p + 255) & ~(uintptr_t)255);
}

extern "C" void kernel_launch(void* const* d_in, const int* in_sizes, int n_in,
                              void* d_out, int out_size, void* d_ws, size_t ws_size,
                              hipStream_t stream) {
    const float* x     = (const float*)d_in[0];
    const int*  eidx   = (const int*)d_in[1];
    const int*  batch  = (const int*)d_in[2];
    const float* w0    = (const float*)d_in[3];
    const float* b0    = (const float*)d_in[4];
    const float* w1    = (const float*)d_in[5];
    const float* b1    = (const float*)d_in[6];
    const float* w2    = (const float*)d_in[7];
    const float* b2    = (const float*)d_in[8];
    const float* w3    = (const float*)d_in[9];
    const float* b3    = (const float*)d_in[10];
    const float* c1w   = (const float*)d_in[11];
    const float* c1b   = (const float*)d_in[12];
    const float* c2w   = (const float*)d_in[13];
    const float* c2b   = (const float*)d_in[14];
    const float* l1w   = (const float*)d_in[15];
    const float* l1b   = (const float*)d_in[16];
    const float* l2w   = (const float*)d_in[17];
    const float* l2b   = (const float*)d_in[18];

    int N = in_sizes[2];              // 50000 nodes
    int E = in_sizes[1] / 2;          // 800000 edges
    int K0 = in_sizes[0] / N;         // 128 input feats
    const int* esrc = eidx;
    const int* edst = eidx + E;

    char* w = (char*)d_ws;
    float* dinv  = (float*)w;             w = align256(w + (size_t)N * 4);
    int*   edeg  = (int*)w;               w = align256(w + (size_t)N * 4);
    int*   offs  = (int*)w;               w = align256(w + (size_t)(N + 1) * 4);
    int*   bsum  = (int*)w;               w = align256(w + 1024);
    float* ts    = (float*)w;             w = align256(w + (size_t)N * 4);
    float* h4    = (float*)w;             w = align256(w + (size_t)N * 4);
    int* starts  = (int*)w;               w = align256(w + (NGRAPH + 1) * 4);
    u16* rank    = (u16*)w;               w = align256(w + (size_t)E * 2);
    u16* csr     = (u16*)w;               w = align256(w + (size_t)E * 2);
    float* Hs    = (float*)w;             w = align256(w + (size_t)N * HID * 4);
    float* h1    = (float*)w;             w = align256(w + (size_t)N * HID * 4);
    float* h2    = (float*)w;             w = align256(w + (size_t)N * HID * 4);
    float* h3    = (float*)w;             w = align256(w + (size_t)N * HID * 4);

    int nb = (N + 255) / 256;             // 196
    int NG = (N + 63) / 64;               // 782
    int NH = (E + 1023) / 1024;           // 782 (4 edges per thread)
    int agg_grid = (N + 3) / 4;

    // zero degree array
    k_zero<<<nb, 256, 0, stream>>>(edeg, N);

    // K1: layer-1 GEMM (raw) || edge histogram+rank || graph starts (even/odd)
    int g1 = 2 * (NG > NH ? NG : NH);
    k_gemm_hist<<<g1, 256, 0, stream>>>(x, w0, Hs, N, K0, NG,
                                        edst, batch, edeg, rank, starts, E, N, NH);

    // CSR offsets (hierarchical scan, stage2+3 fused) + dinv
    k_scan1<<<nb, 256, 0, stream>>>(edeg, offs, bsum, dinv, N);
    k_scan23<<<nb, 256, 0, stream>>>(offs, bsum, N, E, nb);

    // CSR fill (no atomics)
    k_fill<<<(E / 4 + 255) / 256 + 1, 256, 0, stream>>>(esrc, edst, rank, offs, csr, E);

    // layer 1 aggregate (deferred dinv on gathered rows)
    k_agg<true, false><<<agg_grid, 256, 0, stream>>>(Hs, csr, offs, dinv, b0, h1, N, nullptr, nullptr);
    // layer 2
    k_gemm<<<NG, 256, 0, stream>>>(h1, w1, dinv, Hs, N, HID);
    k_agg<false, false><<<agg_grid, 256, 0, stream>>>(Hs, csr, offs, dinv, b1, h2, N, nullptr, nullptr);
    // layer 3 (+ fused layer-4 prescaled GEMV -> ts)
    k_gemm<<<NG, 256, 0, stream>>>(h2, w2, dinv, Hs, N, HID);
    k_agg<false, true><<<agg_grid, 256, 0, stream>>>(Hs, csr, offs, dinv, b2, h3, N, w3, ts);
    // layer 4 aggregate + finish
    k_agg4<<<nb, 256, 0, stream>>>(ts, csr, offs, dinv, b3, h4, N);

    // fused top-30 select + tail
    k_select_tail<<<NGRAPH, 1024, 0, stream>>>(h1, h2, h3, h4, starts,
                                               c1w, c1b, c2w, c2b,
                                               l1w, l1b, l2w, l2b,
                                               (float*)d_out);
}